// Round 2
// 1659.595 us; speedup vs baseline: 1.0599x; 1.0599x over previous
//
#include <hip/hip_runtime.h>
#include <math.h>

#define UNITS 50257
#define UPAD  50304   // 393*128 physical kT rows (zero-filled >= UNITS) — ws layout == round 0
#define NCT   197     // 256-col tiles covering UNITS (197*256 = 50432 logical)
#define NEG   8192
#define CDIM  2048
#define NROWS 2048    // B*S = 2*1024
#define LOG_RANGE_F 10.8249254f  // ln(50258)

// 256x256 tile GEMM geometry
#define BM2 256
#define BN2 256
#define BK2 64
#define ASZ (256 * 64)   // shorts per operand LDS buffer (32 KB)
#define NT2 (CDIM / BK2) // 32 K-tiles

typedef __attribute__((ext_vector_type(8))) short short8;
typedef __attribute__((ext_vector_type(4))) float floatx4;

// ---------- helpers ----------

// float -> bf16 bits, round-to-nearest-even (finite inputs only)
__device__ __forceinline__ unsigned short f2b(float f) {
  unsigned int u = __float_as_uint(f);
  unsigned int lsb = (u >> 16) & 1u;
  u += 0x7fffu + lsb;
  return (unsigned short)(u >> 16);
}

// async global->LDS, 16B per lane. LDS dest must be wave-uniform base + lane*16.
__device__ __forceinline__ void async_copy16(const void* g, void* s) {
  __builtin_amdgcn_global_load_lds(
      (const __attribute__((address_space(1))) void*)g,
      (__attribute__((address_space(3))) void*)s, 16, 0, 0);
}

// log(expected_count(log_uniform_prob(k))) -- mirrors reference fp32 formula
__device__ __forceinline__ float logq_of(int k) {
  float f = (float)k;
  float p = (logf(f + 2.0f) - logf(f + 1.0f)) / LOG_RANGE_F;
  float ec = -expm1f(8192.0f * log1pf(-p));
  return logf(ec);
}

// ---------- small kernels (unchanged) ----------

__global__ void cvt_x_kernel(const float* __restrict__ x, unsigned short* __restrict__ xb) {
  int idx = blockIdx.x * 256 + threadIdx.x;  // < NROWS*CDIM/4
  float4 v = reinterpret_cast<const float4*>(x)[idx];
  unsigned long long r = (unsigned long long)f2b(v.x)
                       | ((unsigned long long)f2b(v.y) << 16)
                       | ((unsigned long long)f2b(v.z) << 32)
                       | ((unsigned long long)f2b(v.w) << 48);
  reinterpret_cast<unsigned long long*>(xb)[idx] = r;
}

// W fp32 [CDIM, UNITS] -> kT bf16 [UPAD, CDIM] (transposed, rows >= UNITS zero-filled)
__global__ void transposeW_kernel(const float* __restrict__ W, unsigned short* __restrict__ kT) {
  __shared__ float tile[32][33];
  int tx = threadIdx.x & 31, ty = threadIdx.x >> 5;  // ty 0..7
  int u0 = blockIdx.x * 32, k0 = blockIdx.y * 32;
  int u = u0 + tx;
#pragma unroll
  for (int r = 0; r < 4; r++) {
    int kk = ty + r * 8;
    tile[kk][tx] = (u < UNITS) ? W[(size_t)(k0 + kk) * UNITS + u] : 0.0f;
  }
  __syncthreads();
#pragma unroll
  for (int r = 0; r < 4; r++) {
    int uu = ty + r * 8;
    kT[(size_t)(u0 + uu) * CDIM + k0 + tx] = f2b(tile[tx][uu]);
  }
}

__global__ void gather_rows_kernel(const unsigned short* __restrict__ kT,
                                   const int* __restrict__ sampled,
                                   unsigned short* __restrict__ kTs) {
  int j = blockIdx.x;
  int s = sampled[j];
  const uint4* src = reinterpret_cast<const uint4*>(kT + (size_t)s * CDIM);
  uint4* dst = reinterpret_cast<uint4*>(kTs + (size_t)j * CDIM);
  dst[threadIdx.x] = src[threadIdx.x];
}

__global__ void prep_logq_kernel(const int* __restrict__ sampled, float* __restrict__ lqs) {
  int j = blockIdx.x * 256 + threadIdx.x;
  if (j < NEG) lqs[j] = logq_of(sampled[j]);
}

// ---------- 256x256 8-wave 4-phase GEMM (T1+T2+T3+T4+T5 stack) ----------
//
// C[m, col] = sum_k A[m,k]*B[col,k] + bias[bidx ? bidx[col] : col]
// A: [NROWS, CDIM] bf16, B: [bRows, CDIM] bf16 (K-contiguous rows). Logical B rows
// beyond bRows are clamped to bRows-1 during staging (their columns are never stored).
//
// Schedule (per K-tile t, 4 phases, 2 barriers each):
//   ph1: ds_read A m0-3 + B n0-1; stage (t+1, B half0) -> Bbuf^1
//   ph2: ds_read A m4-7;          stage (t+1, B half1) -> Bbuf^1
//   ph3: ds_read B n2-3;          stage (t+2, A half0) -> Abuf (A reads all done by
//        ph2's lgkmcnt(0)+barrier -> safe to overwrite)
//   ph4: stage (t+2, A half1) -> Abuf; s_waitcnt vmcnt(4)  (lands all of tile t+1,
//        keeps tile t+2's A halves in flight; vmcnt(0) only for the final 2 tiles)
// LDS swizzle (both-sides, rule #21): physical 16B-col = logical ^ (row&7), realized
// by pre-swizzling the per-lane GLOBAL source (dest stays linear) and XOR-ing the
// ds_read address identically -> conflict-light b128 reads.

// stage one 128x64 bf16 half-tile (16KB): 2 x global_load_lds(16B) over 512 thr.
__device__ __forceinline__ void stage_half(unsigned short* ldsHalf,
                                           const unsigned short* gMat, int rowBase,
                                           size_t kByteOff, int maxRow,
                                           int wave, int lane) {
#pragma unroll
  for (int i = 0; i < 2; i++) {
    int rl = i * 64 + wave * 8 + (lane >> 3);      // row in half; rl&7 == lane>>3
    int gr = rowBase + rl;
    if (gr >= maxRow) gr = maxRow - 1;             // clamp (pad cols never stored)
    const char* g = (const char*)(gMat + (size_t)gr * CDIM) + kByteOff
                  + (((lane & 7) ^ (lane >> 3)) << 4);   // pre-swizzled source col
    unsigned short* s = ldsHalf + (size_t)(i * 64 + wave * 8) * 64 + lane * 8;  // linear dest
    async_copy16(g, s);
  }
}

#define PH_PRE() do { \
    __builtin_amdgcn_s_barrier(); \
    asm volatile("s_waitcnt lgkmcnt(0)" ::: "memory"); \
    __builtin_amdgcn_sched_barrier(0); \
    __builtin_amdgcn_s_setprio(1); \
  } while (0)
#define PH_POST() do { \
    __builtin_amdgcn_s_setprio(0); \
    __builtin_amdgcn_s_barrier(); \
    __builtin_amdgcn_sched_barrier(0); \
  } while (0)

__global__ __launch_bounds__(512, 2)
void gemm256(const unsigned short* __restrict__ A, const unsigned short* __restrict__ B,
             float* __restrict__ Cc, const float* __restrict__ bias,
             const int* __restrict__ bidx, int bRows, int ldc, int colsValid)
{
  __shared__ __align__(16) unsigned short lds[4 * ASZ];  // Abuf0|Abuf1|Bbuf0|Bbuf1 (128 KB)

  const int tid = threadIdx.x;
  const int wave = tid >> 6, lane = tid & 63;
  const int wm = wave >> 2, wn = wave & 3;   // 2x4 wave grid; per-wave out = 128x64

  // bijective XCD-chunk swizzle (gridDim.x % 8 == 0), then 8-row-major:
  // consecutive wg on one XCD share the same 8 M-tiles -> B panels stay L2-hot
  const int qq = (int)gridDim.x >> 3;
  const int wg = ((int)blockIdx.x & 7) * qq + ((int)blockIdx.x >> 3);
  const int m0 = (wg & 7) * BM2;
  const int n0 = (wg >> 3) * BN2;

  const int fr = lane & 15;
  const int cs0 = 8 * ((lane >> 4) ^ (lane & 7));  // swizzled k-slice0 offset, shorts
  const int aRowBase = wm * 128 + fr;
  const int bRowBase = wn * 64 + fr;

  floatx4 acc[8][4];
#pragma unroll
  for (int i = 0; i < 8; i++)
#pragma unroll
    for (int j = 0; j < 4; j++) acc[i][j] = (floatx4){0.f, 0.f, 0.f, 0.f};
  short8 aF[8][2], bF[4][2];

  // ---- prologue: tile0 {A,B} + tile1 {A}; land tile0 (8 loads), keep 4 in flight ----
  {
    unsigned short* A0b = lds;            // A buf 0
    unsigned short* A1b = lds + ASZ;      // A buf 1
    unsigned short* B0b = lds + 2 * ASZ;  // B buf 0
    stage_half(A0b,            A, m0,       0, NROWS, wave, lane);
    stage_half(A0b + 128 * 64, A, m0 + 128, 0, NROWS, wave, lane);
    stage_half(B0b,            B, n0,       0, bRows, wave, lane);
    stage_half(B0b + 128 * 64, B, n0 + 128, 0, bRows, wave, lane);
    stage_half(A1b,            A, m0,       BK2 * 2, NROWS, wave, lane);
    stage_half(A1b + 128 * 64, A, m0 + 128, BK2 * 2, NROWS, wave, lane);
    asm volatile("s_waitcnt vmcnt(4)" ::: "memory");
    __builtin_amdgcn_sched_barrier(0);
    __builtin_amdgcn_s_barrier();
  }

#pragma unroll 1
  for (int t = 0; t < NT2; ++t) {
    unsigned short* Ab = lds + ((t & 1) ? ASZ : 0);
    unsigned short* Bb = lds + 2 * ASZ + ((t & 1) ? ASZ : 0);
    unsigned short* Bn = lds + 2 * ASZ + ((t & 1) ? 0 : ASZ);
    size_t kNext = (size_t)(t + 1) * BK2 * 2;   // bytes
    size_t kNext2 = (size_t)(t + 2) * BK2 * 2;

    // ---- phase 1 ----
#pragma unroll
    for (int mi = 0; mi < 4; ++mi) {
      int ra = (aRowBase + mi * 16) * 64;
      aF[mi][0] = *(const short8*)(Ab + ra + cs0);
      aF[mi][1] = *(const short8*)(Ab + ra + (cs0 ^ 32));
    }
#pragma unroll
    for (int ni = 0; ni < 2; ++ni) {
      int rb = (bRowBase + ni * 16) * 64;
      bF[ni][0] = *(const short8*)(Bb + rb + cs0);
      bF[ni][1] = *(const short8*)(Bb + rb + (cs0 ^ 32));
    }
    if (t + 1 < NT2) stage_half(Bn, B, n0, kNext, bRows, wave, lane);
    PH_PRE();
#pragma unroll
    for (int mi = 0; mi < 4; ++mi)
#pragma unroll
      for (int ni = 0; ni < 2; ++ni) {
        acc[mi][ni] = __builtin_amdgcn_mfma_f32_16x16x32_bf16(aF[mi][0], bF[ni][0], acc[mi][ni], 0, 0, 0);
        acc[mi][ni] = __builtin_amdgcn_mfma_f32_16x16x32_bf16(aF[mi][1], bF[ni][1], acc[mi][ni], 0, 0, 0);
      }
    PH_POST();

    // ---- phase 2 ----
#pragma unroll
    for (int mi = 4; mi < 8; ++mi) {
      int ra = (aRowBase + mi * 16) * 64;
      aF[mi][0] = *(const short8*)(Ab + ra + cs0);
      aF[mi][1] = *(const short8*)(Ab + ra + (cs0 ^ 32));
    }
    if (t + 1 < NT2) stage_half(Bn + 128 * 64, B, n0 + 128, kNext, bRows, wave, lane);
    PH_PRE();
#pragma unroll
    for (int mi = 4; mi < 8; ++mi)
#pragma unroll
      for (int ni = 0; ni < 2; ++ni) {
        acc[mi][ni] = __builtin_amdgcn_mfma_f32_16x16x32_bf16(aF[mi][0], bF[ni][0], acc[mi][ni], 0, 0, 0);
        acc[mi][ni] = __builtin_amdgcn_mfma_f32_16x16x32_bf16(aF[mi][1], bF[ni][1], acc[mi][ni], 0, 0, 0);
      }
    PH_POST();

    // ---- phase 3 ----
#pragma unroll
    for (int ni = 2; ni < 4; ++ni) {
      int rb = (bRowBase + ni * 16) * 64;
      bF[ni][0] = *(const short8*)(Bb + rb + cs0);
      bF[ni][1] = *(const short8*)(Bb + rb + (cs0 ^ 32));
    }
    if (t + 2 < NT2) stage_half(Ab, A, m0, kNext2, NROWS, wave, lane);
    PH_PRE();
#pragma unroll
    for (int mi = 0; mi < 4; ++mi)
#pragma unroll
      for (int ni = 2; ni < 4; ++ni) {
        acc[mi][ni] = __builtin_amdgcn_mfma_f32_16x16x32_bf16(aF[mi][0], bF[ni][0], acc[mi][ni], 0, 0, 0);
        acc[mi][ni] = __builtin_amdgcn_mfma_f32_16x16x32_bf16(aF[mi][1], bF[ni][1], acc[mi][ni], 0, 0, 0);
      }
    PH_POST();

    // ---- phase 4 (counted vmcnt; never 0 until the final 2 tiles) ----
    if (t + 2 < NT2) {
      stage_half(Ab + 128 * 64, A, m0 + 128, kNext2, NROWS, wave, lane);
      asm volatile("s_waitcnt vmcnt(4)" ::: "memory");
    } else {
      asm volatile("s_waitcnt vmcnt(0)" ::: "memory");
    }
    __builtin_amdgcn_sched_barrier(0);
    PH_PRE();
#pragma unroll
    for (int mi = 4; mi < 8; ++mi)
#pragma unroll
      for (int ni = 2; ni < 4; ++ni) {
        acc[mi][ni] = __builtin_amdgcn_mfma_f32_16x16x32_bf16(aF[mi][0], bF[ni][0], acc[mi][ni], 0, 0, 0);
        acc[mi][ni] = __builtin_amdgcn_mfma_f32_16x16x32_bf16(aF[mi][1], bF[ni][1], acc[mi][ni], 0, 0, 0);
      }
    PH_POST();
  }

  // epilogue: C/D layout col=lane&15, row=(lane>>4)*4+reg (m89-verified)
  int rBase = m0 + wm * 128 + ((lane >> 4) << 2);
  int cBase = n0 + wn * 64 + fr;
#pragma unroll
  for (int mi = 0; mi < 8; mi++) {
#pragma unroll
    for (int ni = 0; ni < 4; ni++) {
      int gcol = cBase + ni * 16;
      if (gcol < colsValid) {
        float bv = bias[bidx ? bidx[gcol] : gcol];
#pragma unroll
        for (int v = 0; v < 4; v++) {
          int grow = rBase + mi * 16 + v;
          Cc[(size_t)grow * ldc + gcol] = acc[mi][ni][v] + bv;
        }
      }
    }
  }
}

// ---------- softmax / loss kernels (unchanged) ----------

__global__ void rownorm_kernel(float* __restrict__ logits, const int* __restrict__ targets,
                               float* __restrict__ true_logit)
{
  int i = blockIdx.x, tid = threadIdx.x;
  float* row = logits + (size_t)i * UNITS;
  int t = targets[i];
  __shared__ float red_m[4], red_s[4];

  float m = -INFINITY, s = 0.0f;
  for (int j = tid; j < UNITS; j += 256) {
    float v = row[j];
    if (j == t) true_logit[i] = v;
    float mn = fmaxf(m, v);
    s = s * __expf(m - mn) + __expf(v - mn);
    m = mn;
  }
#pragma unroll
  for (int o = 1; o < 64; o <<= 1) {
    float mo = __shfl_xor(m, o, 64);
    float so = __shfl_xor(s, o, 64);
    float mn = fmaxf(m, mo);
    s = s * __expf(m - mn) + so * __expf(mo - mn);
    m = mn;
  }
  int lane = tid & 63, wv = tid >> 6;
  if (lane == 0) { red_m[wv] = m; red_s[wv] = s; }
  __syncthreads();
  float M = fmaxf(fmaxf(red_m[0], red_m[1]), fmaxf(red_m[2], red_m[3]));
  float S = red_s[0] * __expf(red_m[0] - M) + red_s[1] * __expf(red_m[1] - M)
          + red_s[2] * __expf(red_m[2] - M) + red_s[3] * __expf(red_m[3] - M);
  float inv = 1.0f / S;
  for (int j = tid; j < UNITS; j += 256) {
    row[j] = __expf(row[j] - M) * inv;
  }
}

__global__ void loss_rows_kernel(const float* __restrict__ samp, const int* __restrict__ sampled,
                                 const float* __restrict__ lqs, const int* __restrict__ targets,
                                 const float* __restrict__ true_logit, float* __restrict__ per_ex)
{
  int i = blockIdx.x, tid = threadIdx.x;
  int t = targets[i];
  const float* row = samp + (size_t)i * NEG;
  float tq = true_logit[i] - logq_of(t);
  __shared__ float red[4];
  int lane = tid & 63, wv = tid >> 6;

  float m = tq;
  for (int j = tid; j < NEG; j += 256) {
    if (sampled[j] == t) continue;
    m = fmaxf(m, row[j] - lqs[j]);
  }
#pragma unroll
  for (int o = 32; o > 0; o >>= 1) m = fmaxf(m, __shfl_down(m, o, 64));
  if (lane == 0) red[wv] = m;
  __syncthreads();
  m = fmaxf(fmaxf(red[0], red[1]), fmaxf(red[2], red[3]));
  __syncthreads();

  float s = (tid == 0) ? __expf(tq - m) : 0.0f;
  for (int j = tid; j < NEG; j += 256) {
    if (sampled[j] == t) continue;
    s += __expf(row[j] - lqs[j] - m);
  }
#pragma unroll
  for (int o = 32; o > 0; o >>= 1) s += __shfl_down(s, o, 64);
  if (lane == 0) red[wv] = s;
  __syncthreads();
  if (tid == 0) per_ex[i] = m + logf(red[0] + red[1] + red[2] + red[3]) - tq;
}

__global__ void loss_final_kernel(const float* __restrict__ per_ex, float* __restrict__ out) {
  __shared__ float red[4];
  int tid = threadIdx.x;
  float s = 0.0f;
  for (int j = tid; j < NROWS; j += 256) s += per_ex[j];
#pragma unroll
  for (int o = 32; o > 0; o >>= 1) s += __shfl_down(s, o, 64);
  int lane = tid & 63, wv = tid >> 6;
  if (lane == 0) red[wv] = s;
  __syncthreads();
  if (tid == 0) out[0] = (red[0] + red[1] + red[2] + red[3]) * (1.0f / (float)NROWS);
}

// ---------- launch ----------

extern "C" void kernel_launch(void* const* d_in, const int* in_sizes, int n_in,
                              void* d_out, int out_size, void* d_ws, size_t ws_size,
                              hipStream_t stream) {
  (void)in_sizes; (void)n_in; (void)out_size; (void)ws_size;
  const float* predictions = (const float*)d_in[0];
  const int*   targets     = (const int*)d_in[1];
  const float* W           = (const float*)d_in[2];
  const float* bias        = (const float*)d_in[3];
  const int*   sampled     = (const int*)d_in[4];
  float* out = (float*)d_out;

  // ws layout (~248 MB, byte-identical to round 0): xb | kTs | stats | kT
  char* ws = (char*)d_ws;
  size_t off = 0;
  unsigned short* xb  = (unsigned short*)(ws + off); off += (size_t)NROWS * CDIM * 2;  // 8.39 MB
  unsigned short* kTs = (unsigned short*)(ws + off); off += (size_t)NEG * CDIM * 2;    // 33.55 MB
  float* true_logit = (float*)(ws + off); off += (size_t)NROWS * 4;
  float* per_ex     = (float*)(ws + off); off += (size_t)NROWS * 4;
  float* lqs        = (float*)(ws + off); off += (size_t)NEG * 4;
  off = (off + 255) & ~(size_t)255;
  unsigned short* kT = (unsigned short*)(ws + off);  // UPAD*CDIM*2 = 206 MB
  float* samp = (float*)(ws + off);                  // alias: used only after kT is dead

  float* logits = out;  // [NROWS, UNITS] region of d_out

  cvt_x_kernel<<<(NROWS * CDIM / 4) / 256, 256, 0, stream>>>(predictions, xb);
  transposeW_kernel<<<dim3(UPAD / 32, CDIM / 32), 256, 0, stream>>>(W, kT);
  gather_rows_kernel<<<NEG, 256, 0, stream>>>(kT, sampled, kTs);
  prep_logq_kernel<<<NEG / 256, 256, 0, stream>>>(sampled, lqs);

  // main GEMM: logits = x @ W + bias. grid = 197*8 = 1576 (%8==0)
  gemm256<<<NCT * (NROWS / BM2), 512, 0, stream>>>(
      xb, kT, logits, bias, nullptr, UPAD, UNITS, UNITS);
  // sampled GEMM: samp = x @ W[:,sampled] + bias[sampled]. grid = 32*8 = 256 (%8==0)
  gemm256<<<(NEG / BN2) * (NROWS / BM2), 512, 0, stream>>>(
      xb, kTs, samp, bias, sampled, NEG, NEG, NEG);

  rownorm_kernel<<<NROWS, 256, 0, stream>>>(logits, targets, true_logit);
  loss_rows_kernel<<<NROWS, 256, 0, stream>>>(samp, sampled, lqs, targets, true_logit, per_ex);
  loss_final_kernel<<<1, 256, 0, stream>>>(per_ex, out + (size_t)NROWS * UNITS);
}

// Round 3
// 1614.490 us; speedup vs baseline: 1.0895x; 1.0279x over previous
//
#include <hip/hip_runtime.h>
#include <math.h>

#define UNITS 50257
#define UPAD  50304   // 393*128 physical kT rows (zero-filled >= UNITS)
#define NCT   197     // 256-col tiles covering UNITS (197*256 = 50432 logical)
#define NEG   8192
#define CDIM  2048
#define NROWS 2048    // B*S = 2*1024
#define LOG_RANGE_F 10.8249254f  // ln(50258)

// 256x256 tile GEMM geometry
#define BM2 256
#define BN2 256
#define BK2 64
#define ASZ (256 * 64)   // shorts per operand LDS buffer (32 KB)
#define NT2 (CDIM / BK2) // 32 K-tiles

typedef __attribute__((ext_vector_type(8))) short short8;
typedef __attribute__((ext_vector_type(4))) float floatx4;

// ---------- helpers ----------

// float -> bf16 bits, round-to-nearest-even (finite inputs only)
__device__ __forceinline__ unsigned short f2b(float f) {
  unsigned int u = __float_as_uint(f);
  unsigned int lsb = (u >> 16) & 1u;
  u += 0x7fffu + lsb;
  return (unsigned short)(u >> 16);
}

// async global->LDS, 16B per lane. LDS dest must be wave-uniform base + lane*16.
__device__ __forceinline__ void async_copy16(const void* g, void* s) {
  __builtin_amdgcn_global_load_lds(
      (const __attribute__((address_space(1))) void*)g,
      (__attribute__((address_space(3))) void*)s, 16, 0, 0);
}

// log(expected_count(log_uniform_prob(k))) -- mirrors reference fp32 formula
__device__ __forceinline__ float logq_of(int k) {
  float f = (float)k;
  float p = (logf(f + 2.0f) - logf(f + 1.0f)) / LOG_RANGE_F;
  float ec = -expm1f(8192.0f * log1pf(-p));
  return logf(ec);
}

// ---------- small kernels (unchanged) ----------

__global__ void cvt_x_kernel(const float* __restrict__ x, unsigned short* __restrict__ xb) {
  int idx = blockIdx.x * 256 + threadIdx.x;  // < NROWS*CDIM/4
  float4 v = reinterpret_cast<const float4*>(x)[idx];
  unsigned long long r = (unsigned long long)f2b(v.x)
                       | ((unsigned long long)f2b(v.y) << 16)
                       | ((unsigned long long)f2b(v.z) << 32)
                       | ((unsigned long long)f2b(v.w) << 48);
  reinterpret_cast<unsigned long long*>(xb)[idx] = r;
}

// W fp32 [CDIM, UNITS] -> kT bf16 [UPAD, CDIM] (transposed, rows >= UNITS zero-filled)
__global__ void transposeW_kernel(const float* __restrict__ W, unsigned short* __restrict__ kT) {
  __shared__ float tile[32][33];
  int tx = threadIdx.x & 31, ty = threadIdx.x >> 5;  // ty 0..7
  int u0 = blockIdx.x * 32, k0 = blockIdx.y * 32;
  int u = u0 + tx;
#pragma unroll
  for (int r = 0; r < 4; r++) {
    int kk = ty + r * 8;
    tile[kk][tx] = (u < UNITS) ? W[(size_t)(k0 + kk) * UNITS + u] : 0.0f;
  }
  __syncthreads();
#pragma unroll
  for (int r = 0; r < 4; r++) {
    int uu = ty + r * 8;
    kT[(size_t)(u0 + uu) * CDIM + k0 + tx] = f2b(tile[tx][uu]);
  }
}

__global__ void gather_rows_kernel(const unsigned short* __restrict__ kT,
                                   const int* __restrict__ sampled,
                                   unsigned short* __restrict__ kTs) {
  int j = blockIdx.x;
  int s = sampled[j];
  const uint4* src = reinterpret_cast<const uint4*>(kT + (size_t)s * CDIM);
  uint4* dst = reinterpret_cast<uint4*>(kTs + (size_t)j * CDIM);
  dst[threadIdx.x] = src[threadIdx.x];
}

__global__ void prep_logq_kernel(const int* __restrict__ sampled, float* __restrict__ lqs) {
  int j = blockIdx.x * 256 + threadIdx.x;
  if (j < NEG) lqs[j] = logq_of(sampled[j]);
}

// ---------- 256x256 8-wave 4-phase GEMM, compiler-interleaved phases ----------
//
// C[m, col] = sum_k A[m,k]*B[col,k] + bias[bidx ? bidx[col] : col]
// A: [NROWS, CDIM] bf16, B: [bRows, CDIM] bf16. B rows beyond bRows clamp to
// bRows-1 at staging (their columns are never stored).
//
// Per K-tile t (parity P), 4 phases, ONE barrier each (end). Phase interior is a
// single scheduler region: ds_reads + MFMA interleave via compiler counted waits.
//   P1: [stage B(t+1)h0] reads aF0-3,bF0-1 + MFMA {mi0-3 x ni0-1}
//   P2: [stage B(t+1)h1] reads aF4-7      + MFMA {mi4-7 x ni0-1}
//   P3: [stage A(t+2)h0] reads bF2-3      + MFMA {mi0-3 x ni2-3}
//   P4: [stage A(t+2)h1; vmcnt(4)]          MFMA {mi4-7 x ni2-3}
// WAR proof: every ds_read is consumed by an MFMA in its own phase (auto-wait)
// before that phase's end barrier; staging into a buffer is always >=1 barrier
// after the last phase that read it. RAW: vmcnt(4) at P4 lands tile t+1's A and B
// (12 outstanding -> keeps only A(t+2)'s 4); barrier after it makes that
// cross-wave. vmcnt(0) only for the final two tiles.

#define STAGE(p, OFF) async_copy16((p), sdst + (OFF))

__global__ __launch_bounds__(512, 2)
void gemm256(const unsigned short* __restrict__ A, const unsigned short* __restrict__ B,
             float* __restrict__ Cc, const float* __restrict__ bias,
             const int* __restrict__ bidx, int bRows, int ldc, int colsValid)
{
  __shared__ __align__(16) unsigned short lds[4 * ASZ];  // Abuf0|Abuf1|Bbuf0|Bbuf1 (128 KB)

  const int tid = threadIdx.x;
  const int wave = tid >> 6, lane = tid & 63;
  const int wm = wave >> 2, wn = wave & 3;   // 2x4 wave grid; per-wave out = 128x64

  // bijective XCD-chunk swizzle (gridDim.x % 8 == 0), then 8-row-major
  const int qq = (int)gridDim.x >> 3;
  const int wg = ((int)blockIdx.x & 7) * qq + ((int)blockIdx.x >> 3);
  const int m0 = (wg & 7) * BM2;
  const int n0 = (wg >> 3) * BN2;

  // ---- staging: 8 precomputed per-lane global pointers (advance BK2/tile) ----
  const int srow = wave * 8 + (lane >> 3);
  const int scol = ((lane & 7) ^ (lane >> 3)) << 3;   // pre-swizzled source col (shorts)
  const unsigned short* pA[4];
  const unsigned short* pB[4];
  {
    int r0 = m0 + srow;
    pA[0] = A + (size_t)(r0      ) * CDIM + scol;
    pA[1] = A + (size_t)(r0 +  64) * CDIM + scol;
    pA[2] = A + (size_t)(r0 + 128) * CDIM + scol;
    pA[3] = A + (size_t)(r0 + 192) * CDIM + scol;
    int b0 = n0 + srow;
    int c0 = (b0       < bRows) ? b0       : bRows - 1;
    int c1 = (b0 +  64 < bRows) ? b0 +  64 : bRows - 1;
    int c2 = (b0 + 128 < bRows) ? b0 + 128 : bRows - 1;
    int c3 = (b0 + 192 < bRows) ? b0 + 192 : bRows - 1;
    pB[0] = B + (size_t)c0 * CDIM + scol;
    pB[1] = B + (size_t)c1 * CDIM + scol;
    pB[2] = B + (size_t)c2 * CDIM + scol;
    pB[3] = B + (size_t)c3 * CDIM + scol;
  }
  unsigned short* const sdst = lds + (size_t)(wave * 8) * 64 + lane * 8;  // linear dest base

  // ---- fragment ds_read offsets (loop-invariant; shorts) ----
  const int fr = lane & 15;
  const int cs0 = 8 * ((lane >> 4) ^ (lane & 7));
  const int cs1 = cs0 ^ 32;
  const int aOff0 = (wm * 128 + fr) * 64 + cs0, aOff1 = (wm * 128 + fr) * 64 + cs1;
  const int bOff0 = (wn *  64 + fr) * 64 + cs0, bOff1 = (wn *  64 + fr) * 64 + cs1;

  floatx4 acc[8][4];
#pragma unroll
  for (int i = 0; i < 8; i++)
#pragma unroll
    for (int j = 0; j < 4; j++) acc[i][j] = (floatx4){0.f, 0.f, 0.f, 0.f};
  short8 aF[8][2], bF[4][2];

  // ---- prologue: tile0 {A,B} (8 instr) + tile1 {A} (4 instr); vmcnt(4) lands tile0
  {
    STAGE(pA[0], 0);              STAGE(pA[1], 4096);
    STAGE(pA[2], 8192);           STAGE(pA[3], 12288);
    STAGE(pB[0], 2 * ASZ);        STAGE(pB[1], 2 * ASZ + 4096);
    STAGE(pB[2], 2 * ASZ + 8192); STAGE(pB[3], 2 * ASZ + 12288);
    STAGE(pA[0] + BK2, ASZ);          STAGE(pA[1] + BK2, ASZ + 4096);
    STAGE(pA[2] + BK2, ASZ + 8192);   STAGE(pA[3] + BK2, ASZ + 12288);
    pA[0] += 2 * BK2; pA[1] += 2 * BK2; pA[2] += 2 * BK2; pA[3] += 2 * BK2;
    pB[0] += BK2; pB[1] += BK2; pB[2] += BK2; pB[3] += BK2;
    asm volatile("s_waitcnt vmcnt(4)" ::: "memory");
    __builtin_amdgcn_s_barrier();
  }

#pragma unroll 2
  for (int t = 0; t < NT2; ++t) {
    const int P = t & 1;
    const unsigned short* Ab = lds + (P ? ASZ : 0);
    const unsigned short* Bb = lds + 2 * ASZ + (P ? ASZ : 0);
    const int BO = 2 * ASZ + (P ? 0 : ASZ);   // next-B buffer LDS base (shorts)
    const int AO = (P ? ASZ : 0);             // current-A buffer (staged for t+2)
    const bool s1 = (t + 1 < NT2), s2 = (t + 2 < NT2);

    // ---------- phase 1 ----------
    if (s1) { STAGE(pB[0], BO); STAGE(pB[1], BO + 4096); }
    __builtin_amdgcn_s_setprio(1);
#pragma unroll
    for (int mi = 0; mi < 4; ++mi) {
      aF[mi][0] = *(const short8*)(Ab + aOff0 + mi * 1024);
      aF[mi][1] = *(const short8*)(Ab + aOff1 + mi * 1024);
    }
#pragma unroll
    for (int ni = 0; ni < 2; ++ni) {
      bF[ni][0] = *(const short8*)(Bb + bOff0 + ni * 1024);
      bF[ni][1] = *(const short8*)(Bb + bOff1 + ni * 1024);
    }
#pragma unroll
    for (int mi = 0; mi < 4; ++mi)
#pragma unroll
      for (int ni = 0; ni < 2; ++ni) {
        acc[mi][ni] = __builtin_amdgcn_mfma_f32_16x16x32_bf16(aF[mi][0], bF[ni][0], acc[mi][ni], 0, 0, 0);
        acc[mi][ni] = __builtin_amdgcn_mfma_f32_16x16x32_bf16(aF[mi][1], bF[ni][1], acc[mi][ni], 0, 0, 0);
      }
    __builtin_amdgcn_s_setprio(0);
    __builtin_amdgcn_s_barrier();

    // ---------- phase 2 ----------
    if (s1) {
      STAGE(pB[2], BO + 8192); STAGE(pB[3], BO + 12288);
      pB[0] += BK2; pB[1] += BK2; pB[2] += BK2; pB[3] += BK2;
    }
    __builtin_amdgcn_s_setprio(1);
#pragma unroll
    for (int mi = 4; mi < 8; ++mi) {
      aF[mi][0] = *(const short8*)(Ab + aOff0 + mi * 1024);
      aF[mi][1] = *(const short8*)(Ab + aOff1 + mi * 1024);
    }
#pragma unroll
    for (int mi = 4; mi < 8; ++mi)
#pragma unroll
      for (int ni = 0; ni < 2; ++ni) {
        acc[mi][ni] = __builtin_amdgcn_mfma_f32_16x16x32_bf16(aF[mi][0], bF[ni][0], acc[mi][ni], 0, 0, 0);
        acc[mi][ni] = __builtin_amdgcn_mfma_f32_16x16x32_bf16(aF[mi][1], bF[ni][1], acc[mi][ni], 0, 0, 0);
      }
    __builtin_amdgcn_s_setprio(0);
    __builtin_amdgcn_s_barrier();

    // ---------- phase 3 ----------
    if (s2) { STAGE(pA[0], AO); STAGE(pA[1], AO + 4096); }
    __builtin_amdgcn_s_setprio(1);
#pragma unroll
    for (int ni = 2; ni < 4; ++ni) {
      bF[ni][0] = *(const short8*)(Bb + bOff0 + ni * 1024);
      bF[ni][1] = *(const short8*)(Bb + bOff1 + ni * 1024);
    }
#pragma unroll
    for (int mi = 0; mi < 4; ++mi)
#pragma unroll
      for (int ni = 2; ni < 4; ++ni) {
        acc[mi][ni] = __builtin_amdgcn_mfma_f32_16x16x32_bf16(aF[mi][0], bF[ni][0], acc[mi][ni], 0, 0, 0);
        acc[mi][ni] = __builtin_amdgcn_mfma_f32_16x16x32_bf16(aF[mi][1], bF[ni][1], acc[mi][ni], 0, 0, 0);
      }
    __builtin_amdgcn_s_setprio(0);
    __builtin_amdgcn_s_barrier();

    // ---------- phase 4 (pure MFMA; counted vmcnt lives here) ----------
    if (s2) {
      STAGE(pA[2], AO + 8192); STAGE(pA[3], AO + 12288);
      pA[0] += BK2; pA[1] += BK2; pA[2] += BK2; pA[3] += BK2;
      asm volatile("s_waitcnt vmcnt(4)" ::: "memory");
    } else {
      asm volatile("s_waitcnt vmcnt(0)" ::: "memory");
    }
    __builtin_amdgcn_s_setprio(1);
#pragma unroll
    for (int mi = 4; mi < 8; ++mi)
#pragma unroll
      for (int ni = 2; ni < 4; ++ni) {
        acc[mi][ni] = __builtin_amdgcn_mfma_f32_16x16x32_bf16(aF[mi][0], bF[ni][0], acc[mi][ni], 0, 0, 0);
        acc[mi][ni] = __builtin_amdgcn_mfma_f32_16x16x32_bf16(aF[mi][1], bF[ni][1], acc[mi][ni], 0, 0, 0);
      }
    __builtin_amdgcn_s_setprio(0);
    __builtin_amdgcn_s_barrier();
  }

  // epilogue: C/D layout col=lane&15, row=(lane>>4)*4+reg (m89-verified)
  int rBase = m0 + wm * 128 + ((lane >> 4) << 2);
  int cBase = n0 + wn * 64 + fr;
#pragma unroll
  for (int mi = 0; mi < 8; mi++) {
#pragma unroll
    for (int ni = 0; ni < 4; ni++) {
      int gcol = cBase + ni * 16;
      if (gcol < colsValid) {
        float bv = bias[bidx ? bidx[gcol] : gcol];
#pragma unroll
        for (int v = 0; v < 4; v++) {
          int grow = rBase + mi * 16 + v;
          Cc[(size_t)grow * ldc + gcol] = acc[mi][ni][v] + bv;
        }
      }
    }
  }
}

// ---------- softmax / loss kernels (unchanged) ----------

__global__ void rownorm_kernel(float* __restrict__ logits, const int* __restrict__ targets,
                               float* __restrict__ true_logit)
{
  int i = blockIdx.x, tid = threadIdx.x;
  float* row = logits + (size_t)i * UNITS;
  int t = targets[i];
  __shared__ float red_m[4], red_s[4];

  float m = -INFINITY, s = 0.0f;
  for (int j = tid; j < UNITS; j += 256) {
    float v = row[j];
    if (j == t) true_logit[i] = v;
    float mn = fmaxf(m, v);
    s = s * __expf(m - mn) + __expf(v - mn);
    m = mn;
  }
#pragma unroll
  for (int o = 1; o < 64; o <<= 1) {
    float mo = __shfl_xor(m, o, 64);
    float so = __shfl_xor(s, o, 64);
    float mn = fmaxf(m, mo);
    s = s * __expf(m - mn) + so * __expf(mo - mn);
    m = mn;
  }
  int lane = tid & 63, wv = tid >> 6;
  if (lane == 0) { red_m[wv] = m; red_s[wv] = s; }
  __syncthreads();
  float M = fmaxf(fmaxf(red_m[0], red_m[1]), fmaxf(red_m[2], red_m[3]));
  float S = red_s[0] * __expf(red_m[0] - M) + red_s[1] * __expf(red_m[1] - M)
          + red_s[2] * __expf(red_m[2] - M) + red_s[3] * __expf(red_m[3] - M);
  float inv = 1.0f / S;
  for (int j = tid; j < UNITS; j += 256) {
    row[j] = __expf(row[j] - M) * inv;
  }
}

__global__ void loss_rows_kernel(const float* __restrict__ samp, const int* __restrict__ sampled,
                                 const float* __restrict__ lqs, const int* __restrict__ targets,
                                 const float* __restrict__ true_logit, float* __restrict__ per_ex)
{
  int i = blockIdx.x, tid = threadIdx.x;
  int t = targets[i];
  const float* row = samp + (size_t)i * NEG;
  float tq = true_logit[i] - logq_of(t);
  __shared__ float red[4];
  int lane = tid & 63, wv = tid >> 6;

  float m = tq;
  for (int j = tid; j < NEG; j += 256) {
    if (sampled[j] == t) continue;
    m = fmaxf(m, row[j] - lqs[j]);
  }
#pragma unroll
  for (int o = 32; o > 0; o >>= 1) m = fmaxf(m, __shfl_down(m, o, 64));
  if (lane == 0) red[wv] = m;
  __syncthreads();
  m = fmaxf(fmaxf(red[0], red[1]), fmaxf(red[2], red[3]));
  __syncthreads();

  float s = (tid == 0) ? __expf(tq - m) : 0.0f;
  for (int j = tid; j < NEG; j += 256) {
    if (sampled[j] == t) continue;
    s += __expf(row[j] - lqs[j] - m);
  }
#pragma unroll
  for (int o = 32; o > 0; o >>= 1) s += __shfl_down(s, o, 64);
  if (lane == 0) red[wv] = s;
  __syncthreads();
  if (tid == 0) per_ex[i] = m + logf(red[0] + red[1] + red[2] + red[3]) - tq;
}

__global__ void loss_final_kernel(const float* __restrict__ per_ex, float* __restrict__ out) {
  __shared__ float red[4];
  int tid = threadIdx.x;
  float s = 0.0f;
  for (int j = tid; j < NROWS; j += 256) s += per_ex[j];
#pragma unroll
  for (int o = 32; o > 0; o >>= 1) s += __shfl_down(s, o, 64);
  int lane = tid & 63, wv = tid >> 6;
  if (lane == 0) red[wv] = s;
  __syncthreads();
  if (tid == 0) out[0] = (red[0] + red[1] + red[2] + red[3]) * (1.0f / (float)NROWS);
}

// ---------- launch ----------

extern "C" void kernel_launch(void* const* d_in, const int* in_sizes, int n_in,
                              void* d_out, int out_size, void* d_ws, size_t ws_size,
                              hipStream_t stream) {
  (void)in_sizes; (void)n_in; (void)out_size; (void)ws_size;
  const float* predictions = (const float*)d_in[0];
  const int*   targets     = (const int*)d_in[1];
  const float* W           = (const float*)d_in[2];
  const float* bias        = (const float*)d_in[3];
  const int*   sampled     = (const int*)d_in[4];
  float* out = (float*)d_out;

  // ws layout (~248 MB): xb | kTs | stats | kT (samp aliases kT after main GEMM)
  char* ws = (char*)d_ws;
  size_t off = 0;
  unsigned short* xb  = (unsigned short*)(ws + off); off += (size_t)NROWS * CDIM * 2;  // 8.39 MB
  unsigned short* kTs = (unsigned short*)(ws + off); off += (size_t)NEG * CDIM * 2;    // 33.55 MB
  float* true_logit = (float*)(ws + off); off += (size_t)NROWS * 4;
  float* per_ex     = (float*)(ws + off); off += (size_t)NROWS * 4;
  float* lqs        = (float*)(ws + off); off += (size_t)NEG * 4;
  off = (off + 255) & ~(size_t)255;
  unsigned short* kT = (unsigned short*)(ws + off);  // UPAD*CDIM*2 = 206 MB
  float* samp = (float*)(ws + off);                  // alias: used only after kT is dead

  float* logits = out;  // [NROWS, UNITS] region of d_out

  cvt_x_kernel<<<(NROWS * CDIM / 4) / 256, 256, 0, stream>>>(predictions, xb);
  transposeW_kernel<<<dim3(UPAD / 32, CDIM / 32), 256, 0, stream>>>(W, kT);
  gather_rows_kernel<<<NEG, 256, 0, stream>>>(kT, sampled, kTs);
  prep_logq_kernel<<<NEG / 256, 256, 0, stream>>>(sampled, lqs);

  // main GEMM: logits = x @ W + bias. grid = 197*8 = 1576 (%8==0)
  gemm256<<<NCT * (NROWS / BM2), 512, 0, stream>>>(
      xb, kT, logits, bias, nullptr, UPAD, UNITS, UNITS);
  // sampled GEMM: samp = x @ W[:,sampled] + bias[sampled]. grid = 32*8 = 256 (%8==0)
  gemm256<<<(NEG / BN2) * (NROWS / BM2), 512, 0, stream>>>(
      xb, kTs, samp, bias, sampled, NEG, NEG, NEG);

  rownorm_kernel<<<NROWS, 256, 0, stream>>>(logits, targets, true_logit);
  loss_rows_kernel<<<NROWS, 256, 0, stream>>>(samp, sampled, lqs, targets, true_logit, per_ex);
  loss_final_kernel<<<1, 256, 0, stream>>>(per_ex, out + (size_t)NROWS * UNITS);
}